// Round 2
// baseline (492.654 us; speedup 1.0000x reference)
//
#include <hip/hip_runtime.h>
#include <hip/hip_bf16.h>

#define NN 100000
#define SS 50000
#define KK 32
#define CC 128
#define CHUNKS 6250   // 100000 / 16, exact

// ---------------------------------------------------------------------------
// Kernel 1: P = leaky_relu(word_vec @ W^T + b).
// out (fp32, full answer for non-src rows) and Pb (bf16 copy for attn gather).
// Thread t owns output column o = t&127; half h = t>>7 takes 8 of the 16 rows
// per chunk. W^T staged once per block in LDS as bf16 (32 KB -> 5 blocks/CU).
// A-row bases made wave-uniform via readfirstlane -> scalar broadcast loads.
// ---------------------------------------------------------------------------
__global__ __launch_bounds__(256) void proj_kernel(
    const float* __restrict__ wv,
    const float* __restrict__ W,
    const float* __restrict__ bias,
    __hip_bfloat16* __restrict__ Pb,
    float* __restrict__ out)
{
    __shared__ __hip_bfloat16 sWT[128][128];   // [k][o] = W[o][k]

    const int t = threadIdx.x;

    // Stage W^T (coalesced float4 reads of W; transposed bf16 LDS writes).
    {
        const float4* W4 = (const float4*)W;
        for (int i = t; i < 4096; i += 256) {
            const float4 w = W4[i];
            const int e0 = i * 4;
            const int o = e0 >> 7;
            const int k = e0 & 127;
            sWT[k + 0][o] = __float2bfloat16(w.x);
            sWT[k + 1][o] = __float2bfloat16(w.y);
            sWT[k + 2][o] = __float2bfloat16(w.z);
            sWT[k + 3][o] = __float2bfloat16(w.w);
        }
    }
    __syncthreads();

    const int o = t & 127;
    const int h = t >> 7;          // wave-uniform (waves 0,1 -> 0; 2,3 -> 1)
    const float bo = bias[o];

    for (int chunk = blockIdx.x; chunk < CHUNKS; chunk += gridDim.x) {
        const int rb = __builtin_amdgcn_readfirstlane(chunk * 16 + h * 8);
        const float* a0 = wv + (size_t)rb * CC;

        float acc[8] = {0.f, 0.f, 0.f, 0.f, 0.f, 0.f, 0.f, 0.f};

        #pragma unroll 2
        for (int k = 0; k < CC; k += 4) {
            float4 av[8];
            #pragma unroll
            for (int j = 0; j < 8; j++)
                av[j] = *(const float4*)(a0 + j * CC + k);
            const float w0 = __bfloat162float(sWT[k + 0][o]);
            const float w1 = __bfloat162float(sWT[k + 1][o]);
            const float w2 = __bfloat162float(sWT[k + 2][o]);
            const float w3 = __bfloat162float(sWT[k + 3][o]);
            #pragma unroll
            for (int j = 0; j < 8; j++)
                acc[j] += av[j].x * w0 + av[j].y * w1 + av[j].z * w2 + av[j].w * w3;
        }

        #pragma unroll
        for (int j = 0; j < 8; j++) {
            float v = acc[j] + bo;
            v = v > 0.f ? v : 0.2f * v;
            const size_t off = (size_t)(rb + j) * CC + o;
            out[off] = v;
            Pb[off] = __float2bfloat16(v);
        }
    }
}

// ---------------------------------------------------------------------------
// Kernel 2: one wave per s. lane = r*16 + c (r=0..3 neighbor sub-group,
// c=0..15 column group of 8 floats). Score phase: 16 lanes cooperatively read
// each neighbor row (32B/lane, coalesced), shfl_xor dot-reduce. Aggregation:
// bf16 P rows (256B, coalesced), readlane-broadcast (idx, prob).
// ---------------------------------------------------------------------------
__global__ __launch_bounds__(256) void attn_kernel(
    const float* __restrict__ wv,
    const int* __restrict__ src_idx,
    const int* __restrict__ neighs,
    const int* __restrict__ mask,
    const __hip_bfloat16* __restrict__ Pb,
    float* __restrict__ out)
{
    const int s = (blockIdx.x * 256 + threadIdx.x) >> 6;
    if (s >= SS) return;
    const int lane = threadIdx.x & 63;
    const int c = lane & 15;
    const int r = lane >> 4;

    const int src = src_idx[s];
    const float4* qb = (const float4*)(wv + (size_t)src * CC) + c * 2;
    const float4 q0 = qb[0];
    const float4 q1 = qb[1];

    float sc[8];
    int nbv[8];
    #pragma unroll
    for (int ch = 0; ch < 8; ch++) {
        const int k = ch * 4 + r;
        const int nb = neighs[s * KK + k];
        const int m  = mask[s * KK + k];
        nbv[ch] = nb;
        const float4* kb = (const float4*)(wv + (size_t)nb * CC) + c * 2;
        const float4 b0 = kb[0];
        const float4 b1 = kb[1];
        float d = q0.x * b0.x + q0.y * b0.y + q0.z * b0.z + q0.w * b0.w
                + q1.x * b1.x + q1.y * b1.y + q1.z * b1.z + q1.w * b1.w;
        d += __shfl_xor(d, 1);
        d += __shfl_xor(d, 2);
        d += __shfl_xor(d, 4);
        d += __shfl_xor(d, 8);
        sc[ch] = (m == 1) ? d * 5.0f : -1e6f;
    }

    // softmax over 32 = 8 regs (this r-group) x 4 groups
    float mx = sc[0];
    #pragma unroll
    for (int ch = 1; ch < 8; ch++) mx = fmaxf(mx, sc[ch]);
    mx = fmaxf(mx, __shfl_xor(mx, 16));
    mx = fmaxf(mx, __shfl_xor(mx, 32));

    float p[8];
    float sum = 0.f;
    #pragma unroll
    for (int ch = 0; ch < 8; ch++) {
        p[ch] = __expf(sc[ch] - mx);
        sum += p[ch];
    }
    sum += __shfl_xor(sum, 16);
    sum += __shfl_xor(sum, 32);
    const float inv = 1.0f / sum;
    #pragma unroll
    for (int ch = 0; ch < 8; ch++) p[ch] *= inv;

    // aggregation: lane owns output cols [2*lane, 2*lane+1]
    const unsigned short* Pu = (const unsigned short*)Pb;
    float ax = 0.f, ay = 0.f;
    #pragma unroll
    for (int j = 0; j < 32; j++) {
        const int   idx = __shfl(nbv[j >> 2], (j & 3) << 4);
        const float pj  = __shfl(p[j >> 2], (j & 3) << 4);
        const unsigned int pk =
            *(const unsigned int*)(Pu + (size_t)idx * CC + lane * 2);
        const float v0 = __uint_as_float(pk << 16);
        const float v1 = __uint_as_float(pk & 0xffff0000u);
        ax += pj * v0;
        ay += pj * v1;
    }
    float2 a2 = make_float2(ax, ay);
    *((float2*)(out + (size_t)src * CC) + lane) = a2;
}

extern "C" void kernel_launch(void* const* d_in, const int* in_sizes, int n_in,
                              void* d_out, int out_size, void* d_ws, size_t ws_size,
                              hipStream_t stream)
{
    const float* wv   = (const float*)d_in[0];
    const int*   src  = (const int*)d_in[1];
    const int*   nei  = (const int*)d_in[2];
    const int*   msk  = (const int*)d_in[3];
    const float* W    = (const float*)d_in[4];
    const float* bias = (const float*)d_in[5];
    float* out = (float*)d_out;
    __hip_bfloat16* Pb = (__hip_bfloat16*)d_ws;   // N*CC*2 = 25.6 MB

    proj_kernel<<<1280, 256, 0, stream>>>(wv, W, bias, Pb, out);

    attn_kernel<<<(SS * 64) / 256, 256, 0, stream>>>(wv, src, nei, msk, Pb, out);
}

// Round 3
// 257.256 us; speedup vs baseline: 1.9150x; 1.9150x over previous
//
#include <hip/hip_runtime.h>

#define NN 100000
#define SS 50000
#define KK 32
#define CC 128

typedef _Float16 f16x8 __attribute__((ext_vector_type(8)));
typedef _Float16 f16x4 __attribute__((ext_vector_type(4)));
typedef _Float16 f16x2 __attribute__((ext_vector_type(2)));
typedef float f32x4 __attribute__((ext_vector_type(4)));

// Workspace table T: per row i (512 B stride, 256 halfs):
//   T[i*256 +   0 .. 127] = fp16(word_vec[i])   (written by convert_kernel)
//   T[i*256 + 128 .. 255] = fp16(P[i])          (written by proj_kernel)

// ---------------------------------------------------------------------------
// Kernel 0: wv fp32 -> fp16 into interleaved table.
// ---------------------------------------------------------------------------
__global__ __launch_bounds__(256) void convert_kernel(
    const float* __restrict__ wv, _Float16* __restrict__ T)
{
    const int tid = blockIdx.x * 256 + threadIdx.x;   // 3.2M threads exact
    const int row = tid >> 5;
    const int c4 = (tid & 31) * 4;
    const float4 v = *(const float4*)(wv + (size_t)row * CC + c4);
    f16x4 h;
    h[0] = (_Float16)v.x; h[1] = (_Float16)v.y;
    h[2] = (_Float16)v.z; h[3] = (_Float16)v.w;
    *(f16x4*)(T + (size_t)row * 256 + c4) = h;
}

// ---------------------------------------------------------------------------
// Kernel 1: P = leaky_relu(wv @ W^T + b) via mfma_f32_16x16x32_f16.
// Block = 4 waves, one 16-row chunk per block (6250 blocks, exact).
// Wave w owns cols [w*32, w*32+32): B-frags register-resident (32 VGPR),
// A-frags loaded straight from the fp16 table. Epilogue writes out (fp32)
// and the P_h half of the table.
// ---------------------------------------------------------------------------
__global__ __launch_bounds__(256) void proj_kernel(
    _Float16* __restrict__ T,
    const float* __restrict__ W,
    const float* __restrict__ bias,
    float* __restrict__ out)
{
    const int w = threadIdx.x >> 6;
    const int l = threadIdx.x & 63;
    const int q = l >> 4;      // quad 0..3
    const int c = l & 15;

    // B-frags: B[k][n] = W[n][k]; lane holds n = w*32+nch*16+c,
    // k = kc*32 + q*8 + j  -> 8 contiguous fp32 of W row n.
    f16x8 bf[2][4];
    #pragma unroll
    for (int nch = 0; nch < 2; nch++) {
        const int n = w * 32 + nch * 16 + c;
        const float* Wr = W + (size_t)n * CC;
        #pragma unroll
        for (int kc = 0; kc < 4; kc++) {
            const int k0 = kc * 32 + q * 8;
            const float4 w0 = *(const float4*)(Wr + k0);
            const float4 w1 = *(const float4*)(Wr + k0 + 4);
            f16x8 b;
            b[0] = (_Float16)w0.x; b[1] = (_Float16)w0.y;
            b[2] = (_Float16)w0.z; b[3] = (_Float16)w0.w;
            b[4] = (_Float16)w1.x; b[5] = (_Float16)w1.y;
            b[6] = (_Float16)w1.z; b[7] = (_Float16)w1.w;
            bf[nch][kc] = b;
        }
    }

    const int m0 = blockIdx.x * 16;
    // A-frag: lane holds A[m=c][k = kc*32 + q*8 + j] from the wv_h table.
    const _Float16* Ar = T + (size_t)(m0 + c) * 256 + q * 8;

    f32x4 acc[2] = {{0.f, 0.f, 0.f, 0.f}, {0.f, 0.f, 0.f, 0.f}};
    #pragma unroll
    for (int kc = 0; kc < 4; kc++) {
        const f16x8 a = *(const f16x8*)(Ar + kc * 32);
        acc[0] = __builtin_amdgcn_mfma_f32_16x16x32_f16(a, bf[0][kc], acc[0], 0, 0, 0);
        acc[1] = __builtin_amdgcn_mfma_f32_16x16x32_f16(a, bf[1][kc], acc[1], 0, 0, 0);
    }

    // D layout: col = c (+offsets), row = q*4 + reg.
    #pragma unroll
    for (int nch = 0; nch < 2; nch++) {
        const int col = w * 32 + nch * 16 + c;
        const float bo = bias[col];
        #pragma unroll
        for (int r = 0; r < 4; r++) {
            const int row = m0 + q * 4 + r;
            float v = acc[nch][r] + bo;
            v = v > 0.f ? v : 0.2f * v;
            out[(size_t)row * CC + col] = v;
            T[(size_t)row * 256 + 128 + col] = (_Float16)v;
        }
    }
}

// ---------------------------------------------------------------------------
// Kernel 2: one wave per s. lane = r*16+c. Score phase: 16 lanes read each
// ACTIVE neighbor's fp16 wv row (16B/lane), masked rows never loaded.
// Softmax over 32. Agg phase: skip pj==0 rows (uniform branch), fp16 P rows.
// ---------------------------------------------------------------------------
__global__ __launch_bounds__(256) void attn_kernel(
    const _Float16* __restrict__ T,
    const int* __restrict__ src_idx,
    const int* __restrict__ neighs,
    const int* __restrict__ mask,
    float* __restrict__ out)
{
    const int s = (blockIdx.x * 256 + threadIdx.x) >> 6;
    if (s >= SS) return;
    const int lane = threadIdx.x & 63;
    const int c = lane & 15;
    const int r = lane >> 4;

    const int src = src_idx[s];
    const f16x8 qh = *(const f16x8*)(T + (size_t)src * 256 + c * 8);
    float qf[8];
    #pragma unroll
    for (int j = 0; j < 8; j++) qf[j] = (float)qh[j];

    float sc[8];
    int nbv[8];
    #pragma unroll
    for (int ch = 0; ch < 8; ch++) {
        const int k = ch * 4 + r;
        const int nb = neighs[s * KK + k];
        const int m  = mask[s * KK + k];
        nbv[ch] = nb;
        float d = 0.f;
        if (m == 1) {   // group-uniform: masked rows never fetched
            const f16x8 kh = *(const f16x8*)(T + (size_t)nb * 256 + c * 8);
            #pragma unroll
            for (int j = 0; j < 8; j++) d += qf[j] * (float)kh[j];
            d += __shfl_xor(d, 1);
            d += __shfl_xor(d, 2);
            d += __shfl_xor(d, 4);
            d += __shfl_xor(d, 8);
        }
        sc[ch] = (m == 1) ? d * 5.0f : -1e6f;
    }

    // softmax over 32 (8 regs x 4 r-groups). All-masked s: mx=-1e6, e=1,
    // p=1/32 uniformly -- matches reference exactly.
    float mx = sc[0];
    #pragma unroll
    for (int ch = 1; ch < 8; ch++) mx = fmaxf(mx, sc[ch]);
    mx = fmaxf(mx, __shfl_xor(mx, 16));
    mx = fmaxf(mx, __shfl_xor(mx, 32));

    float p[8];
    float sum = 0.f;
    #pragma unroll
    for (int ch = 0; ch < 8; ch++) {
        p[ch] = __expf(sc[ch] - mx);   // masked: exp(-1e6 - mx) == +0.0f
        sum += p[ch];
    }
    sum += __shfl_xor(sum, 16);
    sum += __shfl_xor(sum, 32);
    const float inv = 1.0f / sum;
    #pragma unroll
    for (int ch = 0; ch < 8; ch++) p[ch] *= inv;

    // aggregation: lane owns output cols [2*lane, 2*lane+1]
    float ax = 0.f, ay = 0.f;
    #pragma unroll
    for (int j = 0; j < 32; j++) {
        const int   idx = __shfl(nbv[j >> 2], (j & 3) << 4);
        const float pj  = __shfl(p[j >> 2], (j & 3) << 4);
        if (pj != 0.f) {   // wave-uniform skip of zero-prob neighbors
            const f16x2 v = *(const f16x2*)(T + (size_t)idx * 256 + 128 + lane * 2);
            ax += pj * (float)v[0];
            ay += pj * (float)v[1];
        }
    }
    *((float2*)(out + (size_t)src * CC) + lane) = make_float2(ax, ay);
}

extern "C" void kernel_launch(void* const* d_in, const int* in_sizes, int n_in,
                              void* d_out, int out_size, void* d_ws, size_t ws_size,
                              hipStream_t stream)
{
    const float* wv   = (const float*)d_in[0];
    const int*   src  = (const int*)d_in[1];
    const int*   nei  = (const int*)d_in[2];
    const int*   msk  = (const int*)d_in[3];
    const float* W    = (const float*)d_in[4];
    const float* bias = (const float*)d_in[5];
    float* out = (float*)d_out;
    _Float16* T = (_Float16*)d_ws;   // 100000 * 512 B = 51.2 MB

    convert_kernel<<<(NN * 32) / 256, 256, 0, stream>>>(wv, T);   // 12500
    proj_kernel<<<NN / 16, 256, 0, stream>>>(T, W, bias, out);    // 6250
    attn_kernel<<<(SS * 64) / 256, 256, 0, stream>>>(T, src, nei, msk, out); // 12500
}

// Round 4
// 225.386 us; speedup vs baseline: 2.1858x; 1.1414x over previous
//
#include <hip/hip_runtime.h>

#define NN 100000
#define SS 50000
#define KK 32
#define CC 128
#define CHUNKS 6250   // NN/16

typedef _Float16 f16x8 __attribute__((ext_vector_type(8)));
typedef _Float16 f16x4 __attribute__((ext_vector_type(4)));
typedef _Float16 f16x2 __attribute__((ext_vector_type(2)));
typedef float f32x4 __attribute__((ext_vector_type(4)));

// Workspace table T: per row i (512 B stride, 256 halfs):
//   T[i*256 +   0 .. 127] = fp16(word_vec[i])   (convert_kernel)
//   T[i*256 + 128 .. 255] = fp16(P[i])          (proj_kernel)

// ---------------------------------------------------------------------------
// Kernel 0: wv fp32 -> fp16 into interleaved table.
// ---------------------------------------------------------------------------
__global__ __launch_bounds__(256) void convert_kernel(
    const float* __restrict__ wv, _Float16* __restrict__ T)
{
    const int tid = blockIdx.x * 256 + threadIdx.x;   // 3.2M threads exact
    const int row = tid >> 5;
    const int c4 = (tid & 31) * 4;
    const float4 v = *(const float4*)(wv + (size_t)row * CC + c4);
    f16x4 h;
    h[0] = (_Float16)v.x; h[1] = (_Float16)v.y;
    h[2] = (_Float16)v.z; h[3] = (_Float16)v.w;
    *(f16x4*)(T + (size_t)row * 256 + c4) = h;
}

// ---------------------------------------------------------------------------
// Kernel 1: P = leaky_relu(wv @ W^T + b) via mfma_f32_16x16x32_f16.
// B-frags (W cols for this wave) loaded ONCE, then grid-stride over 10
// 16-row chunks per block -- amortizes the W-setup that dominated R3.
// ---------------------------------------------------------------------------
__global__ __launch_bounds__(256) void proj_kernel(
    _Float16* __restrict__ T,
    const float* __restrict__ W,
    const float* __restrict__ bias,
    float* __restrict__ out)
{
    const int w = threadIdx.x >> 6;
    const int l = threadIdx.x & 63;
    const int q = l >> 4;      // quad 0..3
    const int c = l & 15;

    // B-frags: B[k][n] = W[n][k]; lane holds n = w*32+nch*16+c,
    // k = kc*32 + q*8 + j.
    f16x8 bf[2][4];
    float bo[2];
    #pragma unroll
    for (int nch = 0; nch < 2; nch++) {
        const int n = w * 32 + nch * 16 + c;
        bo[nch] = bias[n];
        const float* Wr = W + (size_t)n * CC;
        #pragma unroll
        for (int kc = 0; kc < 4; kc++) {
            const int k0 = kc * 32 + q * 8;
            const float4 w0 = *(const float4*)(Wr + k0);
            const float4 w1 = *(const float4*)(Wr + k0 + 4);
            f16x8 b;
            b[0] = (_Float16)w0.x; b[1] = (_Float16)w0.y;
            b[2] = (_Float16)w0.z; b[3] = (_Float16)w0.w;
            b[4] = (_Float16)w1.x; b[5] = (_Float16)w1.y;
            b[6] = (_Float16)w1.z; b[7] = (_Float16)w1.w;
            bf[nch][kc] = b;
        }
    }

    for (int chunk = blockIdx.x; chunk < CHUNKS; chunk += gridDim.x) {
        const int m0 = chunk * 16;
        const _Float16* Ar = T + (size_t)(m0 + c) * 256 + q * 8;

        f32x4 acc[2] = {{0.f, 0.f, 0.f, 0.f}, {0.f, 0.f, 0.f, 0.f}};
        #pragma unroll
        for (int kc = 0; kc < 4; kc++) {
            const f16x8 a = *(const f16x8*)(Ar + kc * 32);
            acc[0] = __builtin_amdgcn_mfma_f32_16x16x32_f16(a, bf[0][kc], acc[0], 0, 0, 0);
            acc[1] = __builtin_amdgcn_mfma_f32_16x16x32_f16(a, bf[1][kc], acc[1], 0, 0, 0);
        }

        // D layout: col = c (+tile offset), row = q*4 + reg.
        #pragma unroll
        for (int nch = 0; nch < 2; nch++) {
            const int col = w * 32 + nch * 16 + c;
            #pragma unroll
            for (int r = 0; r < 4; r++) {
                const int row = m0 + q * 4 + r;
                float v = acc[nch][r] + bo[nch];
                v = v > 0.f ? v : 0.2f * v;
                out[(size_t)row * CC + col] = v;
                T[(size_t)row * 256 + 128 + col] = (_Float16)v;
            }
        }
    }
}

// ---------------------------------------------------------------------------
// Kernel 2: one wave per s. lane = r*16+c. Score phase: fdot2 on packed
// f16x2 (fp32 accumulate), masked rows never fetched. Agg: skip pj==0 rows.
// ---------------------------------------------------------------------------
__global__ __launch_bounds__(256) void attn_kernel(
    const _Float16* __restrict__ T,
    const int* __restrict__ src_idx,
    const int* __restrict__ neighs,
    const int* __restrict__ mask,
    float* __restrict__ out)
{
    const int s = (blockIdx.x * 256 + threadIdx.x) >> 6;
    if (s >= SS) return;
    const int lane = threadIdx.x & 63;
    const int c = lane & 15;
    const int r = lane >> 4;

    const int src = src_idx[s];
    const f16x8 qh = *(const f16x8*)(T + (size_t)src * 256 + c * 8);

    float sc[8];
    int nbv[8];
    #pragma unroll
    for (int ch = 0; ch < 8; ch++) {
        const int k = ch * 4 + r;
        const int nb = neighs[s * KK + k];
        const int m  = mask[s * KK + k];
        nbv[ch] = nb;
        float d = 0.f;
        if (m == 1) {   // group-uniform: masked rows never fetched
            const f16x8 kh = *(const f16x8*)(T + (size_t)nb * 256 + c * 8);
            #pragma unroll
            for (int j = 0; j < 4; j++) {
                f16x2 qa; qa[0] = qh[2 * j]; qa[1] = qh[2 * j + 1];
                f16x2 ka; ka[0] = kh[2 * j]; ka[1] = kh[2 * j + 1];
                d = __builtin_amdgcn_fdot2(qa, ka, d, false);
            }
            d += __shfl_xor(d, 1);
            d += __shfl_xor(d, 2);
            d += __shfl_xor(d, 4);
            d += __shfl_xor(d, 8);
        }
        sc[ch] = (m == 1) ? d * 5.0f : -1e6f;
    }

    // softmax over 32 (8 regs x 4 r-groups). All-masked s: e=1 for all ->
    // uniform 1/32, matching the reference exactly.
    float mx = sc[0];
    #pragma unroll
    for (int ch = 1; ch < 8; ch++) mx = fmaxf(mx, sc[ch]);
    mx = fmaxf(mx, __shfl_xor(mx, 16));
    mx = fmaxf(mx, __shfl_xor(mx, 32));

    float p[8];
    float sum = 0.f;
    #pragma unroll
    for (int ch = 0; ch < 8; ch++) {
        p[ch] = __expf(sc[ch] - mx);   // masked: exp(-1e6 - mx) == +0.0f
        sum += p[ch];
    }
    sum += __shfl_xor(sum, 16);
    sum += __shfl_xor(sum, 32);
    const float inv = 1.0f / sum;
    #pragma unroll
    for (int ch = 0; ch < 8; ch++) p[ch] *= inv;

    // aggregation: lane owns output cols [2*lane, 2*lane+1]
    float ax = 0.f, ay = 0.f;
    #pragma unroll
    for (int j = 0; j < 32; j++) {
        const int   idx = __shfl(nbv[j >> 2], (j & 3) << 4);
        const float pj  = __shfl(p[j >> 2], (j & 3) << 4);
        if (pj != 0.f) {   // wave-uniform skip of zero-prob neighbors
            const f16x2 v = *(const f16x2*)(T + (size_t)idx * 256 + 128 + lane * 2);
            ax += pj * (float)v[0];
            ay += pj * (float)v[1];
        }
    }
    *((float2*)(out + (size_t)src * CC) + lane) = make_float2(ax, ay);
}

extern "C" void kernel_launch(void* const* d_in, const int* in_sizes, int n_in,
                              void* d_out, int out_size, void* d_ws, size_t ws_size,
                              hipStream_t stream)
{
    const float* wv   = (const float*)d_in[0];
    const int*   src  = (const int*)d_in[1];
    const int*   nei  = (const int*)d_in[2];
    const int*   msk  = (const int*)d_in[3];
    const float* W    = (const float*)d_in[4];
    const float* bias = (const float*)d_in[5];
    float* out = (float*)d_out;
    _Float16* T = (_Float16*)d_ws;   // 100000 * 512 B = 51.2 MB

    convert_kernel<<<(NN * 32) / 256, 256, 0, stream>>>(wv, T);       // 12500
    proj_kernel<<<625, 256, 0, stream>>>(T, W, bias, out);            // 10 chunks/block
    attn_kernel<<<(SS * 64) / 256, 256, 0, stream>>>(T, src, nei, msk, out); // 12500
}